// Round 1
// baseline (6673.893 us; speedup 1.0000x reference)
//
#include <hip/hip_runtime.h>
#include <hip/hip_bf16.h>

#define NB 16
#define NN 2048
#define NCHUNK 32                       // col-sum: n-loop split across workgroups
#define ROWS_PER_CHUNK (NN / NCHUNK)    // 64
#define BWG 64                          // row-sum: workgroups per batch
#define ROWS_PER_WG (NN / BWG)          // 32 rows per wg (4 waves x 8 rows)
#define ITERS 100

static constexpr float INV_N  = 1.0f / (float)NN;
static constexpr float NEG_INV_EPS = -10.0f;     // -1/eps, eps = 0.1

__device__ __forceinline__ float bfl(unsigned int p) { return __uint_as_float(p << 16); }
__device__ __forceinline__ float bfh(unsigned int p) { return __uint_as_float(p & 0xffff0000u); }
__device__ __forceinline__ unsigned short f2bf(float f) {
    unsigned int u = __float_as_uint(f);
    unsigned int r = (u + 0x7fffu + ((u >> 16) & 1u)) >> 16;   // RTNE
    return (unsigned short)r;
}
__device__ __forceinline__ float fastrcp(float x) { return __builtin_amdgcn_rcpf(x); }

// ---------------------------------------------------------------- build K (bf16)
__global__ __launch_bounds__(256) void build_K(const float* __restrict__ x,
                                               const float* __restrict__ y,
                                               unsigned short* __restrict__ K) {
    const int n = blockIdx.x, b = blockIdx.y, tid = threadIdx.x;
    const float* xb = x + (size_t)b * 3 * NN;
    const float* yb = y + (size_t)b * 3 * NN;
    const float x0 = xb[n], x1 = xb[NN + n], x2 = xb[2 * NN + n];
    const float xs = x0 * x0 + x1 * x1 + x2 * x2;
    const int m0 = tid * 8;

    const float4 a0 = *(const float4*)(yb + m0);
    const float4 a1 = *(const float4*)(yb + m0 + 4);
    const float4 b0 = *(const float4*)(yb + NN + m0);
    const float4 b1 = *(const float4*)(yb + NN + m0 + 4);
    const float4 c0 = *(const float4*)(yb + 2 * NN + m0);
    const float4 c1 = *(const float4*)(yb + 2 * NN + m0 + 4);
    const float yy0[8] = {a0.x, a0.y, a0.z, a0.w, a1.x, a1.y, a1.z, a1.w};
    const float yy1[8] = {b0.x, b0.y, b0.z, b0.w, b1.x, b1.y, b1.z, b1.w};
    const float yy2[8] = {c0.x, c0.y, c0.z, c0.w, c1.x, c1.y, c1.z, c1.w};

    unsigned short kk[8];
#pragma unroll
    for (int j = 0; j < 8; ++j) {
        const float ys  = yy0[j] * yy0[j] + yy1[j] * yy1[j] + yy2[j] * yy2[j];
        const float dot = x0 * yy0[j] + x1 * yy1[j] + x2 * yy2[j];
        const float C   = fmaxf(xs + ys - 2.0f * dot, 0.0f);
        kk[j] = f2bf(__expf(NEG_INV_EPS * C));
    }
    uint4 pk;
    pk.x = (unsigned int)kk[0] | ((unsigned int)kk[1] << 16);
    pk.y = (unsigned int)kk[2] | ((unsigned int)kk[3] << 16);
    pk.z = (unsigned int)kk[4] | ((unsigned int)kk[5] << 16);
    pk.w = (unsigned int)kk[6] | ((unsigned int)kk[7] << 16);
    *(uint4*)(K + ((size_t)(b * NN + n)) * NN + m0) = pk;
}

// ------------------------------------------------- pass A: S_v[m] += sum_n K[n,m]*u[n]
__global__ __launch_bounds__(256) void pass_colsum(const unsigned short* __restrict__ K,
                                                   const float* __restrict__ u_in,
                                                   float* __restrict__ sv, int first) {
    const int c = blockIdx.x, b = blockIdx.y, tid = threadIdx.x;
    __shared__ float us[ROWS_PER_CHUNK];
    if (tid < ROWS_PER_CHUNK)
        us[tid] = first ? INV_N : u_in[b * NN + c * ROWS_PER_CHUNK + tid];
    __syncthreads();

    float acc0 = 0, acc1 = 0, acc2 = 0, acc3 = 0, acc4 = 0, acc5 = 0, acc6 = 0, acc7 = 0;
    const unsigned short* Kp = K + ((size_t)(b * NN + c * ROWS_PER_CHUNK)) * NN + tid * 8;
#pragma unroll 4
    for (int r = 0; r < ROWS_PER_CHUNK; ++r) {
        const uint4 kv = *(const uint4*)(Kp + (size_t)r * NN);
        const float u = us[r];
        acc0 = fmaf(bfl(kv.x), u, acc0);
        acc1 = fmaf(bfh(kv.x), u, acc1);
        acc2 = fmaf(bfl(kv.y), u, acc2);
        acc3 = fmaf(bfh(kv.y), u, acc3);
        acc4 = fmaf(bfl(kv.z), u, acc4);
        acc5 = fmaf(bfh(kv.z), u, acc5);
        acc6 = fmaf(bfl(kv.w), u, acc6);
        acc7 = fmaf(bfh(kv.w), u, acc7);
    }
    float* p = sv + b * NN + tid * 8;
    atomicAdd(p + 0, acc0); atomicAdd(p + 1, acc1);
    atomicAdd(p + 2, acc2); atomicAdd(p + 3, acc3);
    atomicAdd(p + 4, acc4); atomicAdd(p + 5, acc5);
    atomicAdd(p + 6, acc6); atomicAdd(p + 7, acc7);
}

// ------------------------------------------------- pass B: u[n] = inv_n/(sum_m K[n,m]*v[m] + 1e-8)
// v[m] = inv_n/(svin[m] + 1e-8) computed into per-wave registers. Also zeroes svz for reuse 2 steps later.
__global__ __launch_bounds__(256) void pass_rowsum(const unsigned short* __restrict__ K,
                                                   const float* __restrict__ svin,
                                                   float* __restrict__ u_out,
                                                   float* __restrict__ svz) {
    const int g = blockIdx.x, b = blockIdx.y, tid = threadIdx.x;
    if (tid < 32) svz[(b * BWG + g) * 32 + tid] = 0.0f;
    const int w = tid >> 6, l = tid & 63;
    const float* svb = svin + b * NN;

    float v[4][8];
#pragma unroll
    for (int s = 0; s < 4; ++s) {
        const float4 p0 = *(const float4*)(svb + s * 512 + l * 8);
        const float4 p1 = *(const float4*)(svb + s * 512 + l * 8 + 4);
        v[s][0] = INV_N * fastrcp(p0.x + 1e-8f);
        v[s][1] = INV_N * fastrcp(p0.y + 1e-8f);
        v[s][2] = INV_N * fastrcp(p0.z + 1e-8f);
        v[s][3] = INV_N * fastrcp(p0.w + 1e-8f);
        v[s][4] = INV_N * fastrcp(p1.x + 1e-8f);
        v[s][5] = INV_N * fastrcp(p1.y + 1e-8f);
        v[s][6] = INV_N * fastrcp(p1.z + 1e-8f);
        v[s][7] = INV_N * fastrcp(p1.w + 1e-8f);
    }

    for (int r = 0; r < 8; ++r) {
        const int n = g * ROWS_PER_WG + w * 8 + r;
        const unsigned short* Kp = K + ((size_t)(b * NN + n)) * NN + l * 8;
        float a0 = 0, a1 = 0, a2 = 0, a3 = 0, a4 = 0, a5 = 0, a6 = 0, a7 = 0;
#pragma unroll
        for (int s = 0; s < 4; ++s) {
            const uint4 kv = *(const uint4*)(Kp + s * 512);
            a0 = fmaf(bfl(kv.x), v[s][0], a0);
            a1 = fmaf(bfh(kv.x), v[s][1], a1);
            a2 = fmaf(bfl(kv.y), v[s][2], a2);
            a3 = fmaf(bfh(kv.y), v[s][3], a3);
            a4 = fmaf(bfl(kv.z), v[s][4], a4);
            a5 = fmaf(bfh(kv.z), v[s][5], a5);
            a6 = fmaf(bfl(kv.w), v[s][6], a6);
            a7 = fmaf(bfh(kv.w), v[s][7], a7);
        }
        float sum = ((a0 + a1) + (a2 + a3)) + ((a4 + a5) + (a6 + a7));
#pragma unroll
        for (int off = 32; off > 0; off >>= 1) sum += __shfl_xor(sum, off, 64);
        if (l == 0) u_out[b * NN + n] = INV_N * fastrcp(sum + 1e-8f);
    }
}

// ------------------------------------------------- final: sum_{n,m} u[n]*K[n,m]*C[n,m]*v[m] / B
__global__ __launch_bounds__(256) void final_sum(const unsigned short* __restrict__ K,
                                                 const float* __restrict__ x,
                                                 const float* __restrict__ y,
                                                 const float* __restrict__ svin,
                                                 const float* __restrict__ u_in,
                                                 float* __restrict__ out) {
    const int g = blockIdx.x, b = blockIdx.y, tid = threadIdx.x;
    const int w = tid >> 6, l = tid & 63;
    const float* svb = svin + b * NN;

    float v[4][8];
#pragma unroll
    for (int s = 0; s < 4; ++s) {
        const float4 p0 = *(const float4*)(svb + s * 512 + l * 8);
        const float4 p1 = *(const float4*)(svb + s * 512 + l * 8 + 4);
        v[s][0] = INV_N * fastrcp(p0.x + 1e-8f);
        v[s][1] = INV_N * fastrcp(p0.y + 1e-8f);
        v[s][2] = INV_N * fastrcp(p0.z + 1e-8f);
        v[s][3] = INV_N * fastrcp(p0.w + 1e-8f);
        v[s][4] = INV_N * fastrcp(p1.x + 1e-8f);
        v[s][5] = INV_N * fastrcp(p1.y + 1e-8f);
        v[s][6] = INV_N * fastrcp(p1.z + 1e-8f);
        v[s][7] = INV_N * fastrcp(p1.w + 1e-8f);
    }

    const float* xb = x + (size_t)b * 3 * NN;
    const float* yb = y + (size_t)b * 3 * NN;
    float lacc = 0.0f;

    for (int r = 0; r < 8; ++r) {
        const int n = g * ROWS_PER_WG + w * 8 + r;
        const float x0 = xb[n], x1 = xb[NN + n], x2 = xb[2 * NN + n];
        const float xs = x0 * x0 + x1 * x1 + x2 * x2;
        const float un = u_in[b * NN + n];
        const unsigned short* Kp = K + ((size_t)(b * NN + n)) * NN + l * 8;
        float racc = 0.0f;
#pragma unroll
        for (int s = 0; s < 4; ++s) {
            const int m0 = s * 512 + l * 8;
            const uint4 kv = *(const uint4*)(Kp + s * 512);
            const float4 a0 = *(const float4*)(yb + m0);
            const float4 a1 = *(const float4*)(yb + m0 + 4);
            const float4 b0 = *(const float4*)(yb + NN + m0);
            const float4 b1 = *(const float4*)(yb + NN + m0 + 4);
            const float4 c0 = *(const float4*)(yb + 2 * NN + m0);
            const float4 c1 = *(const float4*)(yb + 2 * NN + m0 + 4);
            const float ky[8]  = {bfl(kv.x), bfh(kv.x), bfl(kv.y), bfh(kv.y),
                                  bfl(kv.z), bfh(kv.z), bfl(kv.w), bfh(kv.w)};
            const float yy0[8] = {a0.x, a0.y, a0.z, a0.w, a1.x, a1.y, a1.z, a1.w};
            const float yy1[8] = {b0.x, b0.y, b0.z, b0.w, b1.x, b1.y, b1.z, b1.w};
            const float yy2[8] = {c0.x, c0.y, c0.z, c0.w, c1.x, c1.y, c1.z, c1.w};
#pragma unroll
            for (int j = 0; j < 8; ++j) {
                const float ys  = yy0[j] * yy0[j] + yy1[j] * yy1[j] + yy2[j] * yy2[j];
                const float dot = x0 * yy0[j] + x1 * yy1[j] + x2 * yy2[j];
                const float C   = fmaxf(xs + ys - 2.0f * dot, 0.0f);
                racc = fmaf(ky[j] * C, v[s][j], racc);
            }
        }
        lacc = fmaf(un, racc, lacc);   // un uniform per row: defer lane-reduction
    }
#pragma unroll
    for (int off = 32; off > 0; off >>= 1) lacc += __shfl_xor(lacc, off, 64);
    __shared__ float red[4];
    if (l == 0) red[w] = lacc;
    __syncthreads();
    if (tid == 0) atomicAdd(out, (red[0] + red[1] + red[2] + red[3]) * (1.0f / (float)NB));
}

extern "C" void kernel_launch(void* const* d_in, const int* in_sizes, int n_in,
                              void* d_out, int out_size, void* d_ws, size_t ws_size,
                              hipStream_t stream) {
    const float* x = (const float*)d_in[0];
    const float* y = (const float*)d_in[1];
    float* out = (float*)d_out;
    char* ws = (char*)d_ws;

    unsigned short* K = (unsigned short*)ws;                 // 16*2048*2048*2 = 134,217,728 B
    const size_t KBYTES = (size_t)NB * NN * NN * 2;
    float* SV = (float*)(ws + KBYTES);                       // 4 rotating sum buffers, 128 KB each
    const size_t SVN = (size_t)NB * NN;
    float* ub = SV + 4 * SVN;                                // u vector, 128 KB

    // SV[0], SV[1] must start zeroed (A_0, A_1 atomically accumulate into them);
    // SV[2], SV[3] are zeroed in-flight by pass_rowsum two steps ahead of reuse.
    hipMemsetAsync(SV, 0, 2 * SVN * sizeof(float), stream);
    hipMemsetAsync(out, 0, sizeof(float), stream);

    build_K<<<dim3(NN, NB), 256, 0, stream>>>(x, y, K);

    for (int i = 0; i < ITERS; ++i) {
        float* sv  = SV + (size_t)(i & 3) * SVN;
        float* svz = SV + (size_t)((i + 2) & 3) * SVN;
        pass_colsum<<<dim3(NCHUNK, NB), 256, 0, stream>>>(K, ub, sv, i == 0 ? 1 : 0);
        pass_rowsum<<<dim3(BWG, NB), 256, 0, stream>>>(K, sv, ub, svz);
    }
    final_sum<<<dim3(BWG, NB), 256, 0, stream>>>(K, x, y, SV + 3 * SVN, ub, out);
}

// Round 2
// 3092.850 us; speedup vs baseline: 2.1578x; 2.1578x over previous
//
#include <hip/hip_runtime.h>
#include <hip/hip_bf16.h>

#define NB 16
#define NN 2048
#define G  64                 // fused: blocks per batch (32 rows each, 4 waves x 8 rows)
#define ITERS 100

static constexpr float INV_N = 1.0f / (float)NN;
static constexpr float NEG_INV_EPS = -10.0f;     // -1/eps, eps = 0.1

__device__ __forceinline__ float bfl(unsigned int p) { return __uint_as_float(p << 16); }
__device__ __forceinline__ float bfh(unsigned int p) { return __uint_as_float(p & 0xffff0000u); }
__device__ __forceinline__ unsigned short f2bf(float f) {
    unsigned int u = __float_as_uint(f);
    unsigned int r = (u + 0x7fffu + ((u >> 16) & 1u)) >> 16;   // RTNE
    return (unsigned short)r;
}
__device__ __forceinline__ float fastrcp(float x) { return __builtin_amdgcn_rcpf(x); }

// ---------------------------------------------------------------- build K (bf16)
__global__ __launch_bounds__(256) void build_K(const float* __restrict__ x,
                                               const float* __restrict__ y,
                                               unsigned short* __restrict__ K) {
    const int n = blockIdx.x, b = blockIdx.y, tid = threadIdx.x;
    const float* xb = x + (size_t)b * 3 * NN;
    const float* yb = y + (size_t)b * 3 * NN;
    const float x0 = xb[n], x1 = xb[NN + n], x2 = xb[2 * NN + n];
    const float xs = x0 * x0 + x1 * x1 + x2 * x2;
    const int m0 = tid * 8;

    const float4 a0 = *(const float4*)(yb + m0);
    const float4 a1 = *(const float4*)(yb + m0 + 4);
    const float4 b0 = *(const float4*)(yb + NN + m0);
    const float4 b1 = *(const float4*)(yb + NN + m0 + 4);
    const float4 c0 = *(const float4*)(yb + 2 * NN + m0);
    const float4 c1 = *(const float4*)(yb + 2 * NN + m0 + 4);
    const float yy0[8] = {a0.x, a0.y, a0.z, a0.w, a1.x, a1.y, a1.z, a1.w};
    const float yy1[8] = {b0.x, b0.y, b0.z, b0.w, b1.x, b1.y, b1.z, b1.w};
    const float yy2[8] = {c0.x, c0.y, c0.z, c0.w, c1.x, c1.y, c1.z, c1.w};

    unsigned short kk[8];
#pragma unroll
    for (int j = 0; j < 8; ++j) {
        const float ys  = yy0[j] * yy0[j] + yy1[j] * yy1[j] + yy2[j] * yy2[j];
        const float dot = x0 * yy0[j] + x1 * yy1[j] + x2 * yy2[j];
        const float C   = fmaxf(xs + ys - 2.0f * dot, 0.0f);
        kk[j] = f2bf(__expf(NEG_INV_EPS * C));
    }
    uint4 pk;
    pk.x = (unsigned int)kk[0] | ((unsigned int)kk[1] << 16);
    pk.y = (unsigned int)kk[2] | ((unsigned int)kk[3] << 16);
    pk.z = (unsigned int)kk[4] | ((unsigned int)kk[5] << 16);
    pk.w = (unsigned int)kk[6] | ((unsigned int)kk[7] << 16);
    *(uint4*)(K + ((size_t)(b * NN + n)) * NN + m0) = pk;
}

// ---------------------------------------------------------------- reduce: v[m] = inv_n/(sum_g PART[g][m] + 1e-8)
__global__ __launch_bounds__(256) void reduce_v(const float* __restrict__ PART,
                                                float* __restrict__ VV) {
    const int t = blockIdx.x * 256 + threadIdx.x;         // t in [0, NB*NN)
    const int b = t >> 11, m = t & (NN - 1);
    const float* p = PART + (size_t)(b * G) * NN + m;
    float s = 0.0f;
#pragma unroll 8
    for (int g = 0; g < G; ++g) s += p[(size_t)g * NN];
    VV[t] = INV_N * fastrcp(s + 1e-8f);
}

// ---------------------------------------------------------------- fused pass (single sweep of K):
//   phase A (skipped when first): u[n] = inv_n/(sum_m K[n,m]*v[m] + 1e-8)   [wave-local, shfl reduce]
//   phase B: PART[g][m] = sum_{n in block} K[n,m]*u[n]                      [regs -> LDS fold -> store]
__global__ __launch_bounds__(256) void fused_pass(const unsigned short* __restrict__ K,
                                                  const float* __restrict__ VV,
                                                  float* __restrict__ u_out,
                                                  float* __restrict__ PART,
                                                  int first) {
    const int g = blockIdx.x, b = blockIdx.y, tid = threadIdx.x;
    const int w = tid >> 6, l = tid & 63;

    float v[4][8];
    if (!first) {
        const float* vb = VV + b * NN;
#pragma unroll
        for (int s = 0; s < 4; ++s) {
            const float4 p0 = *(const float4*)(vb + s * 512 + l * 8);
            const float4 p1 = *(const float4*)(vb + s * 512 + l * 8 + 4);
            v[s][0] = p0.x; v[s][1] = p0.y; v[s][2] = p0.z; v[s][3] = p0.w;
            v[s][4] = p1.x; v[s][5] = p1.y; v[s][6] = p1.z; v[s][7] = p1.w;
        }
    }

    float acc[4][8];
#pragma unroll
    for (int s = 0; s < 4; ++s)
#pragma unroll
        for (int j = 0; j < 8; ++j) acc[s][j] = 0.0f;

#pragma unroll 2
    for (int r = 0; r < 8; ++r) {
        const int n = g * 32 + w * 8 + r;
        const unsigned short* Kp = K + ((size_t)(b * NN + n)) * NN + l * 8;
        uint4 kv[4];
#pragma unroll
        for (int s = 0; s < 4; ++s) kv[s] = *(const uint4*)(Kp + s * 512);

        float u;
        if (first) {
            u = INV_N;
        } else {
            float a0 = 0, a1 = 0, a2 = 0, a3 = 0, a4 = 0, a5 = 0, a6 = 0, a7 = 0;
#pragma unroll
            for (int s = 0; s < 4; ++s) {
                a0 = fmaf(bfl(kv[s].x), v[s][0], a0);
                a1 = fmaf(bfh(kv[s].x), v[s][1], a1);
                a2 = fmaf(bfl(kv[s].y), v[s][2], a2);
                a3 = fmaf(bfh(kv[s].y), v[s][3], a3);
                a4 = fmaf(bfl(kv[s].z), v[s][4], a4);
                a5 = fmaf(bfh(kv[s].z), v[s][5], a5);
                a6 = fmaf(bfl(kv[s].w), v[s][6], a6);
                a7 = fmaf(bfh(kv[s].w), v[s][7], a7);
            }
            float d = ((a0 + a1) + (a2 + a3)) + ((a4 + a5) + (a6 + a7));
#pragma unroll
            for (int off = 32; off > 0; off >>= 1) d += __shfl_xor(d, off, 64);
            u = INV_N * fastrcp(d + 1e-8f);
        }
        if (l == 0) u_out[b * NN + n] = u;

#pragma unroll
        for (int s = 0; s < 4; ++s) {
            acc[s][0] = fmaf(bfl(kv[s].x), u, acc[s][0]);
            acc[s][1] = fmaf(bfh(kv[s].x), u, acc[s][1]);
            acc[s][2] = fmaf(bfl(kv[s].y), u, acc[s][2]);
            acc[s][3] = fmaf(bfh(kv[s].y), u, acc[s][3]);
            acc[s][4] = fmaf(bfl(kv[s].z), u, acc[s][4]);
            acc[s][5] = fmaf(bfh(kv[s].z), u, acc[s][5]);
            acc[s][6] = fmaf(bfl(kv[s].w), u, acc[s][6]);
            acc[s][7] = fmaf(bfh(kv[s].w), u, acc[s][7]);
        }
    }

    // fold 4 waves' column partials via LDS, one store per block
    __shared__ float lds[4][NN];                            // 32 KB
#pragma unroll
    for (int s = 0; s < 4; ++s) {
        *(float4*)&lds[w][s * 512 + l * 8]     = make_float4(acc[s][0], acc[s][1], acc[s][2], acc[s][3]);
        *(float4*)&lds[w][s * 512 + l * 8 + 4] = make_float4(acc[s][4], acc[s][5], acc[s][6], acc[s][7]);
    }
    __syncthreads();
    float o[8];
#pragma unroll
    for (int j = 0; j < 8; ++j)
        o[j] = (lds[0][tid * 8 + j] + lds[1][tid * 8 + j]) +
               (lds[2][tid * 8 + j] + lds[3][tid * 8 + j]);
    float* p = PART + ((size_t)(b * G + g)) * NN + tid * 8;
    *(float4*)(p)     = make_float4(o[0], o[1], o[2], o[3]);
    *(float4*)(p + 4) = make_float4(o[4], o[5], o[6], o[7]);
}

// ---------------------------------------------------------------- final: sum u[n]*K[n,m]*C[n,m]*v[m] / B
__global__ __launch_bounds__(256) void final_sum(const unsigned short* __restrict__ K,
                                                 const float* __restrict__ x,
                                                 const float* __restrict__ y,
                                                 const float* __restrict__ VV,
                                                 const float* __restrict__ u_in,
                                                 float* __restrict__ out) {
    const int g = blockIdx.x, b = blockIdx.y, tid = threadIdx.x;
    const int w = tid >> 6, l = tid & 63;
    const float* vb = VV + b * NN;

    float v[4][8];
#pragma unroll
    for (int s = 0; s < 4; ++s) {
        const float4 p0 = *(const float4*)(vb + s * 512 + l * 8);
        const float4 p1 = *(const float4*)(vb + s * 512 + l * 8 + 4);
        v[s][0] = p0.x; v[s][1] = p0.y; v[s][2] = p0.z; v[s][3] = p0.w;
        v[s][4] = p1.x; v[s][5] = p1.y; v[s][6] = p1.z; v[s][7] = p1.w;
    }

    const float* xb = x + (size_t)b * 3 * NN;
    const float* yb = y + (size_t)b * 3 * NN;
    float lacc = 0.0f;

    for (int r = 0; r < 8; ++r) {
        const int n = g * 32 + w * 8 + r;
        const float x0 = xb[n], x1 = xb[NN + n], x2 = xb[2 * NN + n];
        const float xs = x0 * x0 + x1 * x1 + x2 * x2;
        const float un = u_in[b * NN + n];
        const unsigned short* Kp = K + ((size_t)(b * NN + n)) * NN + l * 8;
        float racc = 0.0f;
#pragma unroll
        for (int s = 0; s < 4; ++s) {
            const int m0 = s * 512 + l * 8;
            const uint4 kv = *(const uint4*)(Kp + s * 512);
            const float4 a0 = *(const float4*)(yb + m0);
            const float4 a1 = *(const float4*)(yb + m0 + 4);
            const float4 b0 = *(const float4*)(yb + NN + m0);
            const float4 b1 = *(const float4*)(yb + NN + m0 + 4);
            const float4 c0 = *(const float4*)(yb + 2 * NN + m0);
            const float4 c1 = *(const float4*)(yb + 2 * NN + m0 + 4);
            const float ky[8]  = {bfl(kv.x), bfh(kv.x), bfl(kv.y), bfh(kv.y),
                                  bfl(kv.z), bfh(kv.z), bfl(kv.w), bfh(kv.w)};
            const float yy0[8] = {a0.x, a0.y, a0.z, a0.w, a1.x, a1.y, a1.z, a1.w};
            const float yy1[8] = {b0.x, b0.y, b0.z, b0.w, b1.x, b1.y, b1.z, b1.w};
            const float yy2[8] = {c0.x, c0.y, c0.z, c0.w, c1.x, c1.y, c1.z, c1.w};
#pragma unroll
            for (int j = 0; j < 8; ++j) {
                const float ys  = yy0[j] * yy0[j] + yy1[j] * yy1[j] + yy2[j] * yy2[j];
                const float dot = x0 * yy0[j] + x1 * yy1[j] + x2 * yy2[j];
                const float C   = fmaxf(xs + ys - 2.0f * dot, 0.0f);
                racc = fmaf(ky[j] * C, v[s][j], racc);
            }
        }
        lacc = fmaf(un, racc, lacc);   // un uniform per row: defer lane-reduction
    }
#pragma unroll
    for (int off = 32; off > 0; off >>= 1) lacc += __shfl_xor(lacc, off, 64);
    __shared__ float red[4];
    if (l == 0) red[w] = lacc;
    __syncthreads();
    if (tid == 0) atomicAdd(out, (red[0] + red[1] + red[2] + red[3]) * (1.0f / (float)NB));
}

extern "C" void kernel_launch(void* const* d_in, const int* in_sizes, int n_in,
                              void* d_out, int out_size, void* d_ws, size_t ws_size,
                              hipStream_t stream) {
    const float* x = (const float*)d_in[0];
    const float* y = (const float*)d_in[1];
    float* out = (float*)d_out;
    char* ws = (char*)d_ws;

    unsigned short* K = (unsigned short*)ws;                 // 16*2048*2048*2 = 134,217,728 B
    const size_t KBYTES = (size_t)NB * NN * NN * 2;
    float* PART = (float*)(ws + KBYTES);                     // 16*64*2048*4 = 8 MiB
    const size_t PARTN = (size_t)NB * G * NN;
    float* VV = PART + PARTN;                                // v vector, 128 KiB
    float* ub = VV + (size_t)NB * NN;                        // u vector, 128 KiB

    hipMemsetAsync(out, 0, sizeof(float), stream);

    build_K<<<dim3(NN, NB), 256, 0, stream>>>(x, y, K);

    // iteration 0 half-step: PART <- K^T u0 (u0 = inv_n), phase A skipped
    fused_pass<<<dim3(G, NB), 256, 0, stream>>>(K, VV, ub, PART, 1);
    for (int i = 0; i < ITERS; ++i) {
        reduce_v<<<dim3(NB * NN / 256), 256, 0, stream>>>(PART, VV);          // v_k
        fused_pass<<<dim3(G, NB), 256, 0, stream>>>(K, VV, ub, PART, 0);      // u_k, PART for v_{k+1}
    }
    // ub = u_100, VV = v_100
    final_sum<<<dim3(G, NB), 256, 0, stream>>>(K, x, y, VV, ub, out);
}